// Round 8
// baseline (54.017 us; speedup 1.0000x reference)
//
#include <hip/hip_runtime.h>
#include <hip/hip_bf16.h>

typedef unsigned short u16;
typedef unsigned int u32;
typedef __attribute__((ext_vector_type(8))) short short8;
typedef __attribute__((ext_vector_type(4))) float f32x4;
typedef __attribute__((ext_vector_type(2))) unsigned int uint2_t;
typedef __attribute__((ext_vector_type(4))) unsigned int uint4_t;
typedef __attribute__((ext_vector_type(2))) float float2_t;

#define L_SEQ 4096
#define NCH 64
#define NBATCH 4
#define NW 8                    // waves per block
#define KVSPAN (L_SEQ / NW)     // fallback kernel: 512 j per wave
#define QB 32                   // fallback kernel: q-rows per block
#define SPLITS 8                // primary kernel: KV splits (one per blockIdx.z)
#define TPS 8                   // tiles (of 64 j) per split

__device__ inline u16 f2bf(float f) {
    union { float f; u32 u; } v; v.f = f;
    u32 r = v.u + 0x7fffu + ((v.u >> 16) & 1u);   // round-to-nearest-even
    return (u16)(r >> 16);
}

// hardware packed f32->bf16 (RNE); low16 = a, high16 = b
__device__ inline u32 cvtpk(float a, float b) {
    u32 r;
    asm("v_cvt_pk_bf16_f32 %0, %1, %2" : "=v"(r) : "v"(a), "v"(b));
    return r;
}

// ---------------- Kernel 1: QKV projection (3x 64x64 channel GEMM) ----------------
// Qt[n][i][c] (bf16, row-major).
// Kp: fragment-order keys:
//   offset(j,c) = (j/16)*1024 + (c/32)*512 + ((c%32)/8)*128 + (j%16)*8 + c%8
//   -> each 64-j tile is a contiguous 4096-elem chunk; frag load = base + lane*8.
// Vp: sigma-permuted fragment-order values (PV contraction slot k=8*hi+e maps to
//   jj = e<4 ? 4*hi+e : 16+4*hi+(e-4)):
//   offset(c,j) = (j/64)*4096 + (c/16)*1024 + ((j%64)/32)*512 + lane*8 + e
//   -> each 64-j tile is a contiguous 4096-elem chunk; frag load = base + lane*8.
__global__ __launch_bounds__(256) void qkv_kernel(
    const float* __restrict__ x,
    const float* __restrict__ wb, const float* __restrict__ bb,
    const float* __restrict__ wc, const float* __restrict__ bc,
    const float* __restrict__ wd, const float* __restrict__ bd,
    u16* __restrict__ Qt, u16* __restrict__ Kp, u16* __restrict__ Vp)
{
    __shared__ float xs[64][64];       // x tile: [c][px]
    __shared__ float wl[3][64][65];    // padded weights: [mat][o][c]

    const int nb  = blockIdx.y;
    const int i0  = blockIdx.x * 64;
    const int tid = threadIdx.x;

    const float* xbase = x + (size_t)nb * NCH * L_SEQ + i0;
    #pragma unroll
    for (int rep = 0; rep < 16; ++rep) {
        int idx = rep * 256 + tid;
        int c = idx >> 6, px = idx & 63;
        xs[c][px] = xbase[(size_t)c * L_SEQ + px];
    }
    const float* wsrc[3] = { wb, wc, wd };
    for (int m = 0; m < 3; ++m) {
        #pragma unroll
        for (int rep = 0; rep < 16; ++rep) {
            int idx = rep * 256 + tid;
            wl[m][idx >> 6][idx & 63] = wsrc[m][idx];
        }
    }
    __syncthreads();

    const int co  = tid & 63;     // output channel
    const int pg  = tid >> 6;     // pixel group 0..3
    const int px0 = pg * 16;

    float accB[16], accC[16], accD[16];
    const float biasB = bb[co], biasC = bc[co], biasD = bd[co];
    #pragma unroll
    for (int p = 0; p < 16; ++p) { accB[p] = biasB; accC[p] = biasC; accD[p] = biasD; }

    for (int c = 0; c < 64; ++c) {
        const float wbv = wl[0][co][c];
        const float wcv = wl[1][co][c];
        const float wdv = wl[2][co][c];
        #pragma unroll
        for (int p = 0; p < 16; ++p) {
            const float xv = xs[c][px0 + p];
            accB[p] += wbv * xv;
            accC[p] += wcv * xv;
            accD[p] += wdv * xv;
        }
    }

    const size_t nbase = (size_t)nb * L_SEQ * NCH;
    const int kbase = (i0 / 16 + pg) * 1024 + (co >> 5) * 512 + ((co & 31) >> 3) * 128 + (co & 7);
    const int vbase = (i0 >> 6) * 4096 + (co >> 4) * 1024 + (pg >> 1) * 512
                    + (co & 15) * 8 + (pg & 1) * 4;

    #pragma unroll
    for (int p = 0; p < 16; ++p) {
        const int i = i0 + px0 + p;
        Kp[nbase + kbase + p * 8] = f2bf(accB[p]);                     // keys    = xb
        Qt[((size_t)(nb * L_SEQ + i)) * NCH + co] = f2bf(accC[p]);     // queries = xc
        Vp[nbase + vbase + (p >> 2) * 128 + (p & 3)] = f2bf(accD[p]);  // values  = xd
    }
}

// ---------------- Kernel 2 (primary): flash attention, q-share + LDS-staged K/V ----
// Block = 8 waves x 32 q-rows each (256 q-rows); all waves walk the SAME j-range
// (split sp: 512 j = 8 tiles of 64), so K/V are staged once per block per tile into
// double-buffered LDS and every wave reads fragments via ds_read_b128 (addresses
// identical across waves). L2 fragment traffic drops 8x vs per-wave global loads.
// Per-wave math core identical to the verified R6 kernel. Partial (m,l,O) per split
// goes to workspace; combine_kernel merges the 8 splits + epilogue.
__global__ __launch_bounds__(512, 4) void attn_kernel2(
    const u16* __restrict__ Qt, const u16* __restrict__ Kp,
    const u16* __restrict__ Vp, u16* __restrict__ Opart,
    float* __restrict__ mlpart)
{
    __shared__ u16 kv[2][2][4096];     // [buf][K|V][64j x 64c], 32 KiB

    const int nb   = blockIdx.y;
    const int qb   = blockIdx.x;       // 0..15 (256 q-rows each)
    const int sp   = blockIdx.z;       // 0..7  (512 j each)
    const int tid  = threadIdx.x;
    const int w    = tid >> 6;
    const int lane = tid & 63;
    const int lo   = lane & 15;
    const int hi   = lane >> 4;

    const int qbase = qb * 256 + w * 32;
    const u16* KpB = Kp + (size_t)nb * L_SEQ * NCH;
    const u16* VpB = Vp + (size_t)nb * NCH * L_SEQ;
    const int T0 = sp * TPS;           // first 64-j tile of this split

    // Q fragments (B operand): col=i=qt*16+lo, k=c=hi*8+e
    short8 qf[2][2];
    #pragma unroll
    for (int qt = 0; qt < 2; ++qt) {
        const u16* qrow = Qt + ((size_t)(nb * L_SEQ + qbase + qt * 16 + lo)) * NCH + hi * 8;
        qf[qt][0] = *(const short8*)(qrow);
        qf[qt][1] = *(const short8*)(qrow + 32);
    }

    const f32x4 zero = { 0.f, 0.f, 0.f, 0.f };
    f32x4 acc_o[2][4];   // [qt][ct]: O^T[c=ct*16+4hi+r][i=qt*16+lo]
    #pragma unroll
    for (int qt = 0; qt < 2; ++qt)
        #pragma unroll
        for (int ct = 0; ct < 4; ++ct) acc_o[qt][ct] = zero;
    float m_[2] = { -3.0e38f, -3.0e38f }, l_[2] = { 0.f, 0.f };

    // prologue: stage tile T0 into buf 0 (512 thr x 16B = 8KB per array)
    {
        short8 k0 = *(const short8*)(KpB + (size_t)T0 * 4096 + tid * 8);
        short8 v0 = *(const short8*)(VpB + (size_t)T0 * 4096 + tid * 8);
        *(short8*)&kv[0][0][tid * 8] = k0;
        *(short8*)&kv[0][1][tid * 8] = v0;
    }

    union PF { u32 u[4]; short8 s; };

    #pragma unroll 1
    for (int t = 0; t < TPS; ++t) {
        const int cur = t & 1;

        // T14 issue-early: next tile's global loads overlap this tile's compute
        short8 knx, vnx;
        if (t < TPS - 1) {
            knx = *(const short8*)(KpB + (size_t)(T0 + t + 1) * 4096 + tid * 8);
            vnx = *(const short8*)(VpB + (size_t)(T0 + t + 1) * 4096 + tid * 8);
        }

        __syncthreads();   // buf[cur] writes (prev iter) visible to all waves

        const u16* kbuf = kv[cur][0];
        const u16* vbuf = kv[cur][1];

        // ---- S^T = K Q^T: s[qt][jt][r] = S[i=qt*16+lo][jt*16 + 4hi + r] ----
        f32x4 s[2][4];
        #pragma unroll
        for (int jt = 0; jt < 4; ++jt) {
            short8 k0 = *(const short8*)(kbuf + jt * 1024 + lane * 8);
            short8 k1 = *(const short8*)(kbuf + jt * 1024 + 512 + lane * 8);
            #pragma unroll
            for (int qt = 0; qt < 2; ++qt) {
                f32x4 a = zero;
                a = __builtin_amdgcn_mfma_f32_16x16x32_bf16(k0, qf[qt][0], a, 0, 0, 0);
                a = __builtin_amdgcn_mfma_f32_16x16x32_bf16(k1, qf[qt][1], a, 0, 0, 0);
                s[qt][jt] = a;
            }
        }

        // ---- online softmax, in-register per q-row + 2 shfl ----
        float scl[2];
        PF pf[2][2];
        #pragma unroll
        for (int qt = 0; qt < 2; ++qt) {
            float rm = fmaxf(
                fmaxf(fmaxf(fmaxf(s[qt][0][0], s[qt][0][1]), fmaxf(s[qt][0][2], s[qt][0][3])),
                      fmaxf(fmaxf(s[qt][1][0], s[qt][1][1]), fmaxf(s[qt][1][2], s[qt][1][3]))),
                fmaxf(fmaxf(fmaxf(s[qt][2][0], s[qt][2][1]), fmaxf(s[qt][2][2], s[qt][2][3])),
                      fmaxf(fmaxf(s[qt][3][0], s[qt][3][1]), fmaxf(s[qt][3][2], s[qt][3][3]))));
            rm = fmaxf(rm, __shfl_xor(rm, 16, 64));
            rm = fmaxf(rm, __shfl_xor(rm, 32, 64));

            const float mn = fmaxf(m_[qt], rm);
            scl[qt] = __expf(m_[qt] - mn);

            float p[4][4];
            float rs = 0.f;
            #pragma unroll
            for (int jt = 0; jt < 4; ++jt)
                #pragma unroll
                for (int r = 0; r < 4; ++r) {
                    p[jt][r] = __expf(s[qt][jt][r] - mn);
                    rs += p[jt][r];
                }
            rs += __shfl_xor(rs, 16, 64);
            rs += __shfl_xor(rs, 32, 64);
            l_[qt] = l_[qt] * scl[qt] + rs;
            m_[qt] = mn;

            pf[qt][0].u[0] = cvtpk(p[0][0], p[0][1]);
            pf[qt][0].u[1] = cvtpk(p[0][2], p[0][3]);
            pf[qt][0].u[2] = cvtpk(p[1][0], p[1][1]);
            pf[qt][0].u[3] = cvtpk(p[1][2], p[1][3]);
            pf[qt][1].u[0] = cvtpk(p[2][0], p[2][1]);
            pf[qt][1].u[1] = cvtpk(p[2][2], p[2][3]);
            pf[qt][1].u[2] = cvtpk(p[3][0], p[3][1]);
            pf[qt][1].u[3] = cvtpk(p[3][2], p[3][3]);
        }

        // ---- rescale O ----
        #pragma unroll
        for (int qt = 0; qt < 2; ++qt)
            #pragma unroll
            for (int ct = 0; ct < 4; ++ct)
                #pragma unroll
                for (int r = 0; r < 4; ++r)
                    acc_o[qt][ct][r] *= scl[qt];

        // ---- O^T += V^T P^T ----
        #pragma unroll
        for (int ct = 0; ct < 4; ++ct) {
            short8 v0 = *(const short8*)(vbuf + ct * 1024 + lane * 8);
            short8 v1 = *(const short8*)(vbuf + ct * 1024 + 512 + lane * 8);
            #pragma unroll
            for (int qt = 0; qt < 2; ++qt) {
                acc_o[qt][ct] = __builtin_amdgcn_mfma_f32_16x16x32_bf16(v0, pf[qt][0].s, acc_o[qt][ct], 0, 0, 0);
                acc_o[qt][ct] = __builtin_amdgcn_mfma_f32_16x16x32_bf16(v1, pf[qt][1].s, acc_o[qt][ct], 0, 0, 0);
            }
        }

        __syncthreads();   // everyone done reading buffers
        if (t < TPS - 1) { // write-late: land next tile in the other buffer
            *(short8*)&kv[cur ^ 1][0][tid * 8] = knx;
            *(short8*)&kv[cur ^ 1][1][tid * 8] = vnx;
        }
    }

    // ---- write split partials: Opart bf16 [sp][nb][q][c], mlpart fp32 [sp][nb][q][2]
    const size_t pb = (size_t)(sp * NBATCH + nb) * L_SEQ;
    #pragma unroll
    for (int qt = 0; qt < 2; ++qt) {
        const int q = qbase + qt * 16 + lo;
        #pragma unroll
        for (int ct = 0; ct < 4; ++ct) {
            uint2_t pk;
            pk[0] = cvtpk(acc_o[qt][ct][0], acc_o[qt][ct][1]);
            pk[1] = cvtpk(acc_o[qt][ct][2], acc_o[qt][ct][3]);
            *(uint2_t*)&Opart[(pb + q) * 64 + ct * 16 + hi * 4] = pk;
        }
        if (hi == 0) {
            float2_t ml; ml[0] = m_[qt]; ml[1] = l_[qt];
            *(float2_t*)&mlpart[(pb + q) * 2] = ml;
        }
    }
}

// ---------------- Kernel 3: combine 8 splits + epilogue ----------------
__global__ __launch_bounds__(256) void combine_kernel(
    const u16* __restrict__ Opart, const float* __restrict__ mlpart,
    const float* __restrict__ x, const float* __restrict__ alphap,
    float* __restrict__ out)
{
    const int gid = blockIdx.x * 256 + threadIdx.x;   // 131072 threads
    const int cg  = gid & 7;
    const int q   = (gid >> 3) & (L_SEQ - 1);
    const int nb  = gid >> 15;
    const int c0  = cg * 8;

    float ms[SPLITS], ls[SPLITS];
    float gm = -3.0e38f;
    #pragma unroll
    for (int s = 0; s < SPLITS; ++s) {
        const float2_t ml = *(const float2_t*)&mlpart[((size_t)(s * NBATCH + nb) * L_SEQ + q) * 2];
        ms[s] = ml[0]; ls[s] = ml[1];
        gm = fmaxf(gm, ml[0]);
    }

    float Ls = 0.f, O[8];
    #pragma unroll
    for (int k = 0; k < 8; ++k) O[k] = 0.f;
    #pragma unroll
    for (int s = 0; s < SPLITS; ++s) {
        const float cf = __expf(ms[s] - gm);
        Ls += ls[s] * cf;
        uint4_t pv = *(const uint4_t*)&Opart[((size_t)(s * NBATCH + nb) * L_SEQ + q) * 64 + c0];
        #pragma unroll
        for (int k2 = 0; k2 < 4; ++k2) {
            union { u32 u; float f; } a, b;
            a.u = (pv[k2] & 0xffffu) << 16;
            b.u = pv[k2] & 0xffff0000u;
            O[k2 * 2]     += cf * a.f;
            O[k2 * 2 + 1] += cf * b.f;
        }
    }

    const float rl    = __builtin_amdgcn_rcpf(Ls);
    const float alpha = alphap[0];
    #pragma unroll
    for (int k = 0; k < 8; ++k) {
        const size_t idx = ((size_t)(nb * NCH + c0 + k)) * L_SEQ + q;
        out[idx] = alpha * O[k] * rl + x[idx];
    }
}

// ---------------- Fallback (R6, proven): split-KV within block, no-LDS loop ----------
__global__ __launch_bounds__(512, 4) void attn_kernel(
    const u16* __restrict__ Qt, const u16* __restrict__ Kp,
    const u16* __restrict__ Vp, const float* __restrict__ x,
    const float* __restrict__ alphap, float* __restrict__ out)
{
    __shared__ float smem[NW][QB * 65];
    __shared__ float mlbuf[NW][QB][2];

    const int nb   = blockIdx.y;
    const int i0   = blockIdx.x * QB;
    const int tid  = threadIdx.x;
    const int w    = tid >> 6;
    const int lane = tid & 63;
    const int lo   = lane & 15;
    const int hi   = lane >> 4;

    short8 qf[2][2];
    #pragma unroll
    for (int qt = 0; qt < 2; ++qt) {
        const u16* qrow = Qt + ((size_t)(nb * L_SEQ + i0 + qt * 16 + lo)) * NCH + hi * 8;
        qf[qt][0] = *(const short8*)(qrow);
        qf[qt][1] = *(const short8*)(qrow + 32);
    }

    const f32x4 zero = { 0.f, 0.f, 0.f, 0.f };
    f32x4 acc_o[2][4];
    #pragma unroll
    for (int qt = 0; qt < 2; ++qt)
        #pragma unroll
        for (int ct = 0; ct < 4; ++ct) acc_o[qt][ct] = zero;
    float m_[2] = { -3.0e38f, -3.0e38f }, l_[2] = { 0.f, 0.f };

    const u16* KpB = Kp + (size_t)nb * L_SEQ * NCH;
    const u16* VpB = Vp + (size_t)nb * NCH * L_SEQ;

    union PF { u32 u[4]; short8 s; };

    #pragma unroll 1
    for (int t = 0; t < KVSPAN / 64; ++t) {
        const int j0 = w * KVSPAN + t * 64;

        f32x4 s[2][4];
        #pragma unroll
        for (int jt = 0; jt < 4; ++jt) {
            const u16* kb = KpB + (size_t)(j0 / 16 + jt) * 1024 + lane * 8;
            short8 k0 = *(const short8*)(kb);
            short8 k1 = *(const short8*)(kb + 512);
            #pragma unroll
            for (int qt = 0; qt < 2; ++qt) {
                f32x4 a = zero;
                a = __builtin_amdgcn_mfma_f32_16x16x32_bf16(k0, qf[qt][0], a, 0, 0, 0);
                a = __builtin_amdgcn_mfma_f32_16x16x32_bf16(k1, qf[qt][1], a, 0, 0, 0);
                s[qt][jt] = a;
            }
        }

        float scl[2];
        PF pf[2][2];
        #pragma unroll
        for (int qt = 0; qt < 2; ++qt) {
            float rm = fmaxf(
                fmaxf(fmaxf(fmaxf(s[qt][0][0], s[qt][0][1]), fmaxf(s[qt][0][2], s[qt][0][3])),
                      fmaxf(fmaxf(s[qt][1][0], s[qt][1][1]), fmaxf(s[qt][1][2], s[qt][1][3]))),
                fmaxf(fmaxf(fmaxf(s[qt][2][0], s[qt][2][1]), fmaxf(s[qt][2][2], s[qt][2][3])),
                      fmaxf(fmaxf(s[qt][3][0], s[qt][3][1]), fmaxf(s[qt][3][2], s[qt][3][3]))));
            rm = fmaxf(rm, __shfl_xor(rm, 16, 64));
            rm = fmaxf(rm, __shfl_xor(rm, 32, 64));

            const float mn = fmaxf(m_[qt], rm);
            scl[qt] = __expf(m_[qt] - mn);

            float p[4][4];
            float rs = 0.f;
            #pragma unroll
            for (int jt = 0; jt < 4; ++jt)
                #pragma unroll
                for (int r = 0; r < 4; ++r) {
                    p[jt][r] = __expf(s[qt][jt][r] - mn);
                    rs += p[jt][r];
                }
            rs += __shfl_xor(rs, 16, 64);
            rs += __shfl_xor(rs, 32, 64);
            l_[qt] = l_[qt] * scl[qt] + rs;
            m_[qt] = mn;

            pf[qt][0].u[0] = cvtpk(p[0][0], p[0][1]);
            pf[qt][0].u[1] = cvtpk(p[0][2], p[0][3]);
            pf[qt][0].u[2] = cvtpk(p[1][0], p[1][1]);
            pf[qt][0].u[3] = cvtpk(p[1][2], p[1][3]);
            pf[qt][1].u[0] = cvtpk(p[2][0], p[2][1]);
            pf[qt][1].u[1] = cvtpk(p[2][2], p[2][3]);
            pf[qt][1].u[2] = cvtpk(p[3][0], p[3][1]);
            pf[qt][1].u[3] = cvtpk(p[3][2], p[3][3]);
        }

        #pragma unroll
        for (int qt = 0; qt < 2; ++qt)
            #pragma unroll
            for (int ct = 0; ct < 4; ++ct)
                #pragma unroll
                for (int r = 0; r < 4; ++r)
                    acc_o[qt][ct][r] *= scl[qt];

        #pragma unroll
        for (int ct = 0; ct < 4; ++ct) {
            const u16* vb = VpB + (size_t)(j0 >> 6) * 4096 + ct * 1024 + lane * 8;
            short8 v0 = *(const short8*)(vb);
            short8 v1 = *(const short8*)(vb + 512);
            #pragma unroll
            for (int qt = 0; qt < 2; ++qt) {
                acc_o[qt][ct] = __builtin_amdgcn_mfma_f32_16x16x32_bf16(v0, pf[qt][0].s, acc_o[qt][ct], 0, 0, 0);
                acc_o[qt][ct] = __builtin_amdgcn_mfma_f32_16x16x32_bf16(v1, pf[qt][1].s, acc_o[qt][ct], 0, 0, 0);
            }
        }
    }

    #pragma unroll
    for (int qt = 0; qt < 2; ++qt)
        #pragma unroll
        for (int ct = 0; ct < 4; ++ct)
            #pragma unroll
            for (int r = 0; r < 4; ++r)
                smem[w][(qt * 16 + lo) * 65 + ct * 16 + hi * 4 + r] = acc_o[qt][ct][r];
    if (hi == 0) {
        #pragma unroll
        for (int qt = 0; qt < 2; ++qt) {
            mlbuf[w][qt * 16 + lo][0] = m_[qt];
            mlbuf[w][qt * 16 + lo][1] = l_[qt];
        }
    }
    __syncthreads();

    const int q  = tid & 31;
    const int c0 = (tid >> 5) * 4;

    float gm = -3.0e38f;
    #pragma unroll
    for (int s2 = 0; s2 < NW; ++s2) gm = fmaxf(gm, mlbuf[s2][q][0]);

    float Ls = 0.f, O[4] = { 0.f, 0.f, 0.f, 0.f };
    #pragma unroll
    for (int s2 = 0; s2 < NW; ++s2) {
        const float cf = __expf(mlbuf[s2][q][0] - gm);
        Ls += mlbuf[s2][q][1] * cf;
        #pragma unroll
        for (int k = 0; k < 4; ++k)
            O[k] += smem[s2][q * 65 + c0 + k] * cf;
    }
    const float rl    = __builtin_amdgcn_rcpf(Ls);
    const float alpha = alphap[0];

    #pragma unroll
    for (int k = 0; k < 4; ++k) {
        const size_t idx = ((size_t)(nb * NCH + c0 + k)) * L_SEQ + i0 + q;
        out[idx] = alpha * O[k] * rl + x[idx];
    }
}

extern "C" void kernel_launch(void* const* d_in, const int* in_sizes, int n_in,
                              void* d_out, int out_size, void* d_ws, size_t ws_size,
                              hipStream_t stream) {
    const float* x     = (const float*)d_in[0];
    const float* wb    = (const float*)d_in[1];
    const float* bb    = (const float*)d_in[2];
    const float* wc    = (const float*)d_in[3];
    const float* bc    = (const float*)d_in[4];
    const float* wd    = (const float*)d_in[5];
    const float* bd    = (const float*)d_in[6];
    const float* alpha = (const float*)d_in[7];

    const size_t elems = (size_t)NBATCH * L_SEQ * NCH;  // 1,048,576
    u16* Qt = (u16*)d_ws;
    u16* Kp = Qt + elems;
    u16* Vp = Kp + elems;
    u16* Opart = Vp + elems;                               // SPLITS*elems u16
    float* mlpart = (float*)(Opart + (size_t)SPLITS * elems);

    const size_t need = (3 + SPLITS) * elems * 2
                      + (size_t)SPLITS * NBATCH * L_SEQ * 2 * 4;  // ~24.1 MB

    qkv_kernel<<<dim3(L_SEQ / 64, NBATCH), 256, 0, stream>>>(
        x, wb, bb, wc, bc, wd, bd, Qt, Kp, Vp);

    if (ws_size >= need) {
        attn_kernel2<<<dim3(L_SEQ / 256, NBATCH, SPLITS), 512, 0, stream>>>(
            Qt, Kp, Vp, Opart, mlpart);
        combine_kernel<<<dim3(NBATCH * L_SEQ * 8 / 256), 256, 0, stream>>>(
            Opart, mlpart, x, alpha, (float*)d_out);
    } else {
        attn_kernel<<<dim3(L_SEQ / QB, NBATCH), 512, 0, stream>>>(
            Qt, Kp, Vp, x, alpha, (float*)d_out);
    }
}

// Round 9
// 52.624 us; speedup vs baseline: 1.0265x; 1.0265x over previous
//
#include <hip/hip_runtime.h>
#include <hip/hip_bf16.h>

typedef unsigned short u16;
typedef unsigned int u32;
typedef __attribute__((ext_vector_type(8))) short short8;
typedef __attribute__((ext_vector_type(4))) float f32x4;
typedef __attribute__((ext_vector_type(2))) unsigned int uint2_t;

#define L_SEQ 4096
#define NCH 64
#define NBATCH 4
#define NW 16                   // waves per block = KV splits
#define KVSPAN (L_SEQ / NW)     // 256 j per wave (4 tiles of 64)
#define QB 32                   // q-rows per block (shared by all waves)
#define SMSTRIDE 76             // u16 stride for partial-O rows (2-way-free banks)

__device__ inline u16 f2bf(float f) {
    union { float f; u32 u; } v; v.f = f;
    u32 r = v.u + 0x7fffu + ((v.u >> 16) & 1u);   // round-to-nearest-even
    return (u16)(r >> 16);
}

// hardware packed f32->bf16 (RNE); low16 = a, high16 = b
__device__ inline u32 cvtpk(float a, float b) {
    u32 r;
    asm("v_cvt_pk_bf16_f32 %0, %1, %2" : "=v"(r) : "v"(a), "v"(b));
    return r;
}

// ---------------- Kernel 1: QKV projection (3x 64x64 channel GEMM) ----------------
// Qt[n][i][c] (bf16, row-major).
// Kp: fragment-order keys:
//   offset(j,c) = (j/16)*1024 + (c/32)*512 + ((c%32)/8)*128 + (j%16)*8 + c%8
//   -> frag load = tile base + lane*8 elems (coalesced 1KB per instruction).
// Vp: sigma-permuted fragment-order values (PV contraction slot k=8*hi+e maps to
//   jj = e<4 ? 4*hi+e : 16+4*hi+(e-4)):
//   offset(c,j) = (j/64)*4096 + (c/16)*1024 + ((j%64)/32)*512 + lane*8 + e.
__global__ __launch_bounds__(256) void qkv_kernel(
    const float* __restrict__ x,
    const float* __restrict__ wb, const float* __restrict__ bb,
    const float* __restrict__ wc, const float* __restrict__ bc,
    const float* __restrict__ wd, const float* __restrict__ bd,
    u16* __restrict__ Qt, u16* __restrict__ Kp, u16* __restrict__ Vp)
{
    __shared__ float xs[64][64];       // x tile: [c][px]
    __shared__ float wl[3][64][65];    // padded weights: [mat][o][c]

    const int nb  = blockIdx.y;
    const int i0  = blockIdx.x * 64;
    const int tid = threadIdx.x;

    const float* xbase = x + (size_t)nb * NCH * L_SEQ + i0;
    #pragma unroll
    for (int rep = 0; rep < 16; ++rep) {
        int idx = rep * 256 + tid;
        int c = idx >> 6, px = idx & 63;
        xs[c][px] = xbase[(size_t)c * L_SEQ + px];
    }
    const float* wsrc[3] = { wb, wc, wd };
    for (int m = 0; m < 3; ++m) {
        #pragma unroll
        for (int rep = 0; rep < 16; ++rep) {
            int idx = rep * 256 + tid;
            wl[m][idx >> 6][idx & 63] = wsrc[m][idx];
        }
    }
    __syncthreads();

    const int co  = tid & 63;     // output channel
    const int pg  = tid >> 6;     // pixel group 0..3
    const int px0 = pg * 16;

    float accB[16], accC[16], accD[16];
    const float biasB = bb[co], biasC = bc[co], biasD = bd[co];
    #pragma unroll
    for (int p = 0; p < 16; ++p) { accB[p] = biasB; accC[p] = biasC; accD[p] = biasD; }

    for (int c = 0; c < 64; ++c) {
        const float wbv = wl[0][co][c];
        const float wcv = wl[1][co][c];
        const float wdv = wl[2][co][c];
        #pragma unroll
        for (int p = 0; p < 16; ++p) {
            const float xv = xs[c][px0 + p];
            accB[p] += wbv * xv;
            accC[p] += wcv * xv;
            accD[p] += wdv * xv;
        }
    }

    const size_t nbase = (size_t)nb * L_SEQ * NCH;
    const int kbase = (i0 / 16 + pg) * 1024 + (co >> 5) * 512 + ((co & 31) >> 3) * 128 + (co & 7);
    const int vbase = (i0 >> 6) * 4096 + (co >> 4) * 1024 + (pg >> 1) * 512
                    + (co & 15) * 8 + (pg & 1) * 4;

    #pragma unroll
    for (int p = 0; p < 16; ++p) {
        const int i = i0 + px0 + p;
        Kp[nbase + kbase + p * 8] = f2bf(accB[p]);                     // keys    = xb
        Qt[((size_t)(nb * L_SEQ + i)) * NCH + co] = f2bf(accC[p]);     // queries = xc
        Vp[nbase + vbase + (p >> 2) * 128 + (p & 3)] = f2bf(accD[p]);  // values  = xd
    }
}

// ---------------- Kernel 2: flash attention, 16-way split-KV, no-LDS loop ----------
// Block = 16 waves sharing one 32-row q-tile; wave w covers j in [w*256,(w+1)*256).
// Per-wave math core identical to the verified R6 kernel (VGPR=64): swapped QK^T,
// in-register softmax (15-op tree + 2 shfl), lane-local sigma-packed P, coalesced
// fragment loads. 16 splits double total waves to 8192 (32/CU) for latency hiding;
// partial O stored bf16 in LDS so block LDS = exactly 80KB -> 2 blocks/CU.
__global__ __launch_bounds__(1024, 4) void attn_kernel(
    const u16* __restrict__ Qt, const u16* __restrict__ Kp,
    const u16* __restrict__ Vp, const float* __restrict__ x,
    const float* __restrict__ alphap, float* __restrict__ out)
{
    __shared__ u16 smem[NW][QB * SMSTRIDE];   // per-wave partial O^ (bf16), 77.8KB
    __shared__ float mlbuf[NW][QB][2];        // per-wave (m,l), 4KB

    const int nb   = blockIdx.y;
    const int i0   = blockIdx.x * QB;
    const int tid  = threadIdx.x;
    const int w    = tid >> 6;
    const int lane = tid & 63;
    const int lo   = lane & 15;
    const int hi   = lane >> 4;

    // Q fragments (B operand): col=i=qt*16+lo, k=c=hi*8+e
    short8 qf[2][2];
    #pragma unroll
    for (int qt = 0; qt < 2; ++qt) {
        const u16* qrow = Qt + ((size_t)(nb * L_SEQ + i0 + qt * 16 + lo)) * NCH + hi * 8;
        qf[qt][0] = *(const short8*)(qrow);
        qf[qt][1] = *(const short8*)(qrow + 32);
    }

    const f32x4 zero = { 0.f, 0.f, 0.f, 0.f };
    f32x4 acc_o[2][4];   // [qt][ct]: O^T[c=ct*16+4hi+r][i=qt*16+lo]
    #pragma unroll
    for (int qt = 0; qt < 2; ++qt)
        #pragma unroll
        for (int ct = 0; ct < 4; ++ct) acc_o[qt][ct] = zero;
    float m_[2] = { -3.0e38f, -3.0e38f }, l_[2] = { 0.f, 0.f };

    const u16* KpB = Kp + (size_t)nb * L_SEQ * NCH;
    const u16* VpB = Vp + (size_t)nb * NCH * L_SEQ;

    union PF { u32 u[4]; short8 s; };

    #pragma unroll 1
    for (int t = 0; t < KVSPAN / 64; ++t) {
        const int j0 = w * KVSPAN + t * 64;

        // ---- S^T = K Q^T: s[qt][jt][r] = S[i=qt*16+lo][j0 + jt*16 + 4hi + r] ----
        f32x4 s[2][4];
        #pragma unroll
        for (int jt = 0; jt < 4; ++jt) {
            const u16* kb = KpB + (size_t)(j0 / 16 + jt) * 1024 + lane * 8;
            short8 k0 = *(const short8*)(kb);
            short8 k1 = *(const short8*)(kb + 512);
            #pragma unroll
            for (int qt = 0; qt < 2; ++qt) {
                f32x4 a = zero;
                a = __builtin_amdgcn_mfma_f32_16x16x32_bf16(k0, qf[qt][0], a, 0, 0, 0);
                a = __builtin_amdgcn_mfma_f32_16x16x32_bf16(k1, qf[qt][1], a, 0, 0, 0);
                s[qt][jt] = a;
            }
        }

        // ---- online softmax, in-register per q-row + 2 shfl ----
        float scl[2];
        PF pf[2][2];
        #pragma unroll
        for (int qt = 0; qt < 2; ++qt) {
            float rm = fmaxf(
                fmaxf(fmaxf(fmaxf(s[qt][0][0], s[qt][0][1]), fmaxf(s[qt][0][2], s[qt][0][3])),
                      fmaxf(fmaxf(s[qt][1][0], s[qt][1][1]), fmaxf(s[qt][1][2], s[qt][1][3]))),
                fmaxf(fmaxf(fmaxf(s[qt][2][0], s[qt][2][1]), fmaxf(s[qt][2][2], s[qt][2][3])),
                      fmaxf(fmaxf(s[qt][3][0], s[qt][3][1]), fmaxf(s[qt][3][2], s[qt][3][3]))));
            rm = fmaxf(rm, __shfl_xor(rm, 16, 64));
            rm = fmaxf(rm, __shfl_xor(rm, 32, 64));

            const float mn = fmaxf(m_[qt], rm);
            scl[qt] = __expf(m_[qt] - mn);

            float p[4][4];
            float rs = 0.f;
            #pragma unroll
            for (int jt = 0; jt < 4; ++jt)
                #pragma unroll
                for (int r = 0; r < 4; ++r) {
                    p[jt][r] = __expf(s[qt][jt][r] - mn);
                    rs += p[jt][r];
                }
            rs += __shfl_xor(rs, 16, 64);
            rs += __shfl_xor(rs, 32, 64);
            l_[qt] = l_[qt] * scl[qt] + rs;
            m_[qt] = mn;

            pf[qt][0].u[0] = cvtpk(p[0][0], p[0][1]);
            pf[qt][0].u[1] = cvtpk(p[0][2], p[0][3]);
            pf[qt][0].u[2] = cvtpk(p[1][0], p[1][1]);
            pf[qt][0].u[3] = cvtpk(p[1][2], p[1][3]);
            pf[qt][1].u[0] = cvtpk(p[2][0], p[2][1]);
            pf[qt][1].u[1] = cvtpk(p[2][2], p[2][3]);
            pf[qt][1].u[2] = cvtpk(p[3][0], p[3][1]);
            pf[qt][1].u[3] = cvtpk(p[3][2], p[3][3]);
        }

        // ---- rescale O ----
        #pragma unroll
        for (int qt = 0; qt < 2; ++qt)
            #pragma unroll
            for (int ct = 0; ct < 4; ++ct)
                #pragma unroll
                for (int r = 0; r < 4; ++r)
                    acc_o[qt][ct][r] *= scl[qt];

        // ---- O^T += V^T P^T; sigma-ordered coalesced V fragment loads ----
        #pragma unroll
        for (int ct = 0; ct < 4; ++ct) {
            const u16* vb = VpB + (size_t)(j0 >> 6) * 4096 + ct * 1024 + lane * 8;
            short8 v0 = *(const short8*)(vb);
            short8 v1 = *(const short8*)(vb + 512);
            #pragma unroll
            for (int qt = 0; qt < 2; ++qt) {
                acc_o[qt][ct] = __builtin_amdgcn_mfma_f32_16x16x32_bf16(v0, pf[qt][0].s, acc_o[qt][ct], 0, 0, 0);
                acc_o[qt][ct] = __builtin_amdgcn_mfma_f32_16x16x32_bf16(v1, pf[qt][1].s, acc_o[qt][ct], 0, 0, 0);
            }
        }
    }

    // ---- write per-wave partial state to LDS (O as packed bf16) ----
    #pragma unroll
    for (int qt = 0; qt < 2; ++qt)
        #pragma unroll
        for (int ct = 0; ct < 4; ++ct) {
            uint2_t pk;
            pk[0] = cvtpk(acc_o[qt][ct][0], acc_o[qt][ct][1]);
            pk[1] = cvtpk(acc_o[qt][ct][2], acc_o[qt][ct][3]);
            *(uint2_t*)&smem[w][(qt * 16 + lo) * SMSTRIDE + ct * 16 + hi * 4] = pk;
        }
    if (hi == 0) {
        #pragma unroll
        for (int qt = 0; qt < 2; ++qt) {
            mlbuf[w][qt * 16 + lo][0] = m_[qt];
            mlbuf[w][qt * 16 + lo][1] = l_[qt];
        }
    }
    __syncthreads();

    // ---- combine 16 partials + epilogue ----
    // thread -> (q = tid&31, c0 = (tid>>5)*2): covers 32 q x 64 c with 1024 threads
    const int q  = tid & 31;
    const int c0 = (tid >> 5) * 2;

    float gm = -3.0e38f;
    #pragma unroll
    for (int s2 = 0; s2 < NW; ++s2) gm = fmaxf(gm, mlbuf[s2][q][0]);

    float Ls = 0.f, O0 = 0.f, O1 = 0.f;
    #pragma unroll
    for (int s2 = 0; s2 < NW; ++s2) {
        const float cf = __expf(mlbuf[s2][q][0] - gm);
        Ls += mlbuf[s2][q][1] * cf;
        const u32 pk = *(const u32*)&smem[s2][q * SMSTRIDE + c0];
        union { u32 u; float f; } a, b;
        a.u = (pk & 0xffffu) << 16;
        b.u = pk & 0xffff0000u;
        O0 += cf * a.f;
        O1 += cf * b.f;
    }
    const float rl    = __builtin_amdgcn_rcpf(Ls);
    const float alpha = alphap[0];

    const size_t base0 = ((size_t)(nb * NCH + c0)) * L_SEQ + i0 + q;
    out[base0]         = alpha * O0 * rl + x[base0];
    out[base0 + L_SEQ] = alpha * O1 * rl + x[base0 + L_SEQ];
}

extern "C" void kernel_launch(void* const* d_in, const int* in_sizes, int n_in,
                              void* d_out, int out_size, void* d_ws, size_t ws_size,
                              hipStream_t stream) {
    const float* x     = (const float*)d_in[0];
    const float* wb    = (const float*)d_in[1];
    const float* bb    = (const float*)d_in[2];
    const float* wc    = (const float*)d_in[3];
    const float* bc    = (const float*)d_in[4];
    const float* wd    = (const float*)d_in[5];
    const float* bd    = (const float*)d_in[6];
    const float* alpha = (const float*)d_in[7];

    const size_t elems = (size_t)NBATCH * L_SEQ * NCH;  // 1,048,576
    u16* Qt = (u16*)d_ws;
    u16* Kp = Qt + elems;
    u16* Vp = Kp + elems;

    qkv_kernel<<<dim3(L_SEQ / 64, NBATCH), 256, 0, stream>>>(
        x, wb, bb, wc, bc, wd, bd, Qt, Kp, Vp);
    attn_kernel<<<dim3(L_SEQ / QB, NBATCH), 1024, 0, stream>>>(
        Qt, Kp, Vp, x, alpha, (float*)d_out);
}

// Round 11
// 39.975 us; speedup vs baseline: 1.3513x; 1.3164x over previous
//
#include <hip/hip_runtime.h>
#include <hip/hip_bf16.h>

typedef unsigned short u16;
typedef unsigned char u8;
typedef unsigned int u32;
typedef long long i64;
typedef __attribute__((ext_vector_type(4))) float f32x4;
typedef __attribute__((ext_vector_type(4))) unsigned int u32x4;

#define L_SEQ 4096
#define NCH 64
#define NBATCH 4
#define NW 8                    // waves per block = KV splits
#define KVSPAN (L_SEQ / NW)     // 512 j per wave (8 tiles of 64)
#define QB 32                   // q-rows per block (shared by all waves)
#define DEFER_THR 4.0f          // T13: P bounded by e^4=54.6 << fp8 max 448

__device__ inline u16 f2bf(float f) {
    union { float f; u32 u; } v; v.f = f;
    u32 r = v.u + 0x7fffu + ((v.u >> 16) & 1u);
    return (u16)(r >> 16);
}

// packed f32 pair -> 2x fp8 e4m3 into low (WORD=false) or high (WORD=true) 16 bits.
// WORD must be an immediate -> template parameter.
template <bool WORD>
__device__ inline u32 pk_fp8(float a, float b, u32 old) {
    return (u32)__builtin_amdgcn_cvt_pk_fp8_f32(a, b, (int)old, WORD);
}
__device__ inline u8 fp8_1(float a) {
    return (u8)(__builtin_amdgcn_cvt_pk_fp8_f32(a, a, 0, false) & 0xff);
}

// ---------------- Kernel 1: QKV projection -> fp8 fragment-order workspace --------
// Qp8[n][i][c] bytes (row-major; B-frag = two 8B loads, prologue only).
// Kp8: A-frag order for mfma(K,Q): byte(jb,lane,b): lane=hi*16+(j%16),
//   b<8 -> c=hi*8+b (frag0), b>=8 -> c=32+hi*8+(b-8) (frag1).
//   addr = jb*1024 + lane*16 + b  -> attn tile load = base + lane*16 (dwordx4).
// Vp8: sigma-permuted A-frag order for PV: sigma(h,e)= e<4 ? 4h+e : 16+4h+(e-4);
//   byte(tile,ct,lane,b): c=ct*16+(lane&15), jl=(b>=8?32:0)+sigma(lane>>4, b&7).
//   addr = tile*4096 + ct*1024 + lane*16 + b.
__global__ __launch_bounds__(256) void qkv_kernel(
    const float* __restrict__ x,
    const float* __restrict__ wb, const float* __restrict__ bb,
    const float* __restrict__ wc, const float* __restrict__ bc,
    const float* __restrict__ wd, const float* __restrict__ bd,
    u8* __restrict__ Qp8, u8* __restrict__ Kp8, u8* __restrict__ Vp8)
{
    __shared__ float xs[64][64];       // x tile: [c][px]
    __shared__ float wl[3][64][65];    // padded weights: [mat][o][c]

    const int nb  = blockIdx.y;
    const int i0  = blockIdx.x * 64;
    const int tid = threadIdx.x;

    const float* xbase = x + (size_t)nb * NCH * L_SEQ + i0;
    #pragma unroll
    for (int rep = 0; rep < 16; ++rep) {
        int idx = rep * 256 + tid;
        int c = idx >> 6, px = idx & 63;
        xs[c][px] = xbase[(size_t)c * L_SEQ + px];
    }
    const float* wsrc[3] = { wb, wc, wd };
    for (int m = 0; m < 3; ++m) {
        #pragma unroll
        for (int rep = 0; rep < 16; ++rep) {
            int idx = rep * 256 + tid;
            wl[m][idx >> 6][idx & 63] = wsrc[m][idx];
        }
    }
    __syncthreads();

    const int co  = tid & 63;     // output channel
    const int pg  = tid >> 6;     // pixel group 0..3
    const int px0 = pg * 16;

    float accB[16], accC[16], accD[16];
    const float biasB = bb[co], biasC = bc[co], biasD = bd[co];
    #pragma unroll
    for (int p = 0; p < 16; ++p) { accB[p] = biasB; accC[p] = biasC; accD[p] = biasD; }

    for (int c = 0; c < 64; ++c) {
        const float wbv = wl[0][co][c];
        const float wcv = wl[1][co][c];
        const float wdv = wl[2][co][c];
        #pragma unroll
        for (int p = 0; p < 16; ++p) {
            const float xv = xs[c][px0 + p];
            accB[p] += wbv * xv;
            accC[p] += wcv * xv;
            accD[p] += wdv * xv;
        }
    }

    const size_t nbase = (size_t)nb * L_SEQ * NCH;   // bytes per batch = 262144
    const int jb     = i0 / 16 + pg;
    const int kbase8 = ((co & 31) >> 3) * 256 + (co >> 5) * 8 + (co & 7);
    const int vbase8 = (i0 >> 6) * 4096 + (co >> 4) * 1024 + (co & 15) * 16
                     + (pg >> 1) * 8 + (pg & 1) * 4;

    #pragma unroll
    for (int p = 0; p < 16; ++p) {
        const int i = i0 + px0 + p;
        Kp8[nbase + jb * 1024 + kbase8 + p * 16] = fp8_1(accB[p]);   // keys    = xb
        Qp8[nbase + (size_t)i * 64 + co]         = fp8_1(accC[p]);   // queries = xc
    }
    #pragma unroll
    for (int pq = 0; pq < 4; ++pq) {                                  // values = xd
        u32 wv = pk_fp8<false>(accD[pq * 4 + 0], accD[pq * 4 + 1], 0);
        wv     = pk_fp8<true >(accD[pq * 4 + 2], accD[pq * 4 + 3], wv);
        *(u32*)&Vp8[nbase + vbase8 + pq * 256] = wv;
    }
}

// ---------------- Kernel 2: flash attention, fp8 fragments, split-KV, no-LDS loop --
// R6 structure (proven): 8 waves share one 32-row q-tile, wave w covers 512 j.
// fp8 halves fragment bytes AND load count (8 dwordx4/tile). Swapped QK^T,
// in-register softmax + 2 shfl, lane-local sigma-packed fp8 P, T13 defer-max.
__global__ __launch_bounds__(512, 4) void attn_kernel(
    const u8* __restrict__ Qp8, const u8* __restrict__ Kp8,
    const u8* __restrict__ Vp8, const float* __restrict__ x,
    const float* __restrict__ alphap, float* __restrict__ out)
{
    __shared__ float smem[NW][QB * 65];   // per-wave partial O [q][c], pad 65
    __shared__ float mlbuf[NW][QB][2];

    const int nb   = blockIdx.y;
    const int i0   = blockIdx.x * QB;
    const int tid  = threadIdx.x;
    const int w    = tid >> 6;
    const int lane = tid & 63;
    const int lo   = lane & 15;
    const int hi   = lane >> 4;

    // Q fragments (B operand): col=i=qt*16+lo, k=c=hi*8+e
    i64 qf[2][2];
    #pragma unroll
    for (int qt = 0; qt < 2; ++qt) {
        const u8* qrow = Qp8 + (size_t)(nb * L_SEQ + i0 + qt * 16 + lo) * 64;
        qf[qt][0] = *(const i64*)(qrow + hi * 8);
        qf[qt][1] = *(const i64*)(qrow + 32 + hi * 8);
    }

    const f32x4 zero = { 0.f, 0.f, 0.f, 0.f };
    f32x4 acc_o[2][4];   // [qt][ct]: O^T[c=ct*16+4hi+r][i=qt*16+lo]
    #pragma unroll
    for (int qt = 0; qt < 2; ++qt)
        #pragma unroll
        for (int ct = 0; ct < 4; ++ct) acc_o[qt][ct] = zero;
    float m_[2] = { -3.0e38f, -3.0e38f }, l_[2] = { 0.f, 0.f };

    const u8* KpB = Kp8 + (size_t)nb * L_SEQ * NCH;
    const u8* VpB = Vp8 + (size_t)nb * NCH * L_SEQ;

    union F8 { u32 u[2]; i64 ll; };

    #pragma unroll 1
    for (int t = 0; t < KVSPAN / 64; ++t) {
        const int j0 = w * KVSPAN + t * 64;

        // ---- S^T = K Q^T: s[qt][jt][r] = S[i=qt*16+lo][j0 + jt*16 + 4hi + r] ----
        f32x4 s[2][4];
        #pragma unroll
        for (int jt = 0; jt < 4; ++jt) {
            const u32x4 kw = *(const u32x4*)(KpB + (size_t)(j0 / 16 + jt) * 1024 + lane * 16);
            F8 k0, k1;
            k0.u[0] = kw[0]; k0.u[1] = kw[1];
            k1.u[0] = kw[2]; k1.u[1] = kw[3];
            #pragma unroll
            for (int qt = 0; qt < 2; ++qt) {
                f32x4 a = zero;
                a = __builtin_amdgcn_mfma_f32_16x16x32_fp8_fp8(k0.ll, qf[qt][0], a, 0, 0, 0);
                a = __builtin_amdgcn_mfma_f32_16x16x32_fp8_fp8(k1.ll, qf[qt][1], a, 0, 0, 0);
                s[qt][jt] = a;
            }
        }

        // ---- online softmax (in-register + 2 shfl) with T13 defer-max ----
        F8 pf[2][2];
        #pragma unroll
        for (int qt = 0; qt < 2; ++qt) {
            float rm = fmaxf(
                fmaxf(fmaxf(fmaxf(s[qt][0][0], s[qt][0][1]), fmaxf(s[qt][0][2], s[qt][0][3])),
                      fmaxf(fmaxf(s[qt][1][0], s[qt][1][1]), fmaxf(s[qt][1][2], s[qt][1][3]))),
                fmaxf(fmaxf(fmaxf(s[qt][2][0], s[qt][2][1]), fmaxf(s[qt][2][2], s[qt][2][3])),
                      fmaxf(fmaxf(s[qt][3][0], s[qt][3][1]), fmaxf(s[qt][3][2], s[qt][3][3]))));
            rm = fmaxf(rm, __shfl_xor(rm, 16, 64));
            rm = fmaxf(rm, __shfl_xor(rm, 32, 64));

            // defer: keep old max if all rows grew by <= THR (P <= e^4, fp8-safe)
            if (!__all(rm <= m_[qt] + DEFER_THR)) {
                const float mn  = fmaxf(m_[qt], rm);
                const float scl = __expf(m_[qt] - mn);
                l_[qt] *= scl;
                m_[qt] = mn;
                #pragma unroll
                for (int ct = 0; ct < 4; ++ct)
                    #pragma unroll
                    for (int r = 0; r < 4; ++r)
                        acc_o[qt][ct][r] *= scl;
            }
            const float mn = m_[qt];

            float p[4][4];
            float rs = 0.f;
            #pragma unroll
            for (int jt = 0; jt < 4; ++jt)
                #pragma unroll
                for (int r = 0; r < 4; ++r) {
                    p[jt][r] = __expf(s[qt][jt][r] - mn);
                    rs += p[jt][r];
                }
            rs += __shfl_xor(rs, 16, 64);
            rs += __shfl_xor(rs, 32, 64);
            l_[qt] += rs;

            // pack P to fp8 in sigma order: frag f, byte e -> jj = f*32 + sigma(hi,e)
            pf[qt][0].u[0] = pk_fp8<true>(p[0][2], p[0][3], pk_fp8<false>(p[0][0], p[0][1], 0));
            pf[qt][0].u[1] = pk_fp8<true>(p[1][2], p[1][3], pk_fp8<false>(p[1][0], p[1][1], 0));
            pf[qt][1].u[0] = pk_fp8<true>(p[2][2], p[2][3], pk_fp8<false>(p[2][0], p[2][1], 0));
            pf[qt][1].u[1] = pk_fp8<true>(p[3][2], p[3][3], pk_fp8<false>(p[3][0], p[3][1], 0));
        }

        // ---- O^T += V^T P^T; sigma-ordered coalesced fp8 V fragment loads ----
        #pragma unroll
        for (int ct = 0; ct < 4; ++ct) {
            const u32x4 vw = *(const u32x4*)(VpB + (size_t)(j0 >> 6) * 4096 + ct * 1024 + lane * 16);
            F8 v0, v1;
            v0.u[0] = vw[0]; v0.u[1] = vw[1];
            v1.u[0] = vw[2]; v1.u[1] = vw[3];
            #pragma unroll
            for (int qt = 0; qt < 2; ++qt) {
                acc_o[qt][ct] = __builtin_amdgcn_mfma_f32_16x16x32_fp8_fp8(v0.ll, pf[qt][0].ll, acc_o[qt][ct], 0, 0, 0);
                acc_o[qt][ct] = __builtin_amdgcn_mfma_f32_16x16x32_fp8_fp8(v1.ll, pf[qt][1].ll, acc_o[qt][ct], 0, 0, 0);
            }
        }
    }

    // ---- write per-wave partial state to LDS: smem[w][q][c] ----
    #pragma unroll
    for (int qt = 0; qt < 2; ++qt)
        #pragma unroll
        for (int ct = 0; ct < 4; ++ct)
            #pragma unroll
            for (int r = 0; r < 4; ++r)
                smem[w][(qt * 16 + lo) * 65 + ct * 16 + hi * 4 + r] = acc_o[qt][ct][r];
    if (hi == 0) {
        #pragma unroll
        for (int qt = 0; qt < 2; ++qt) {
            mlbuf[w][qt * 16 + lo][0] = m_[qt];
            mlbuf[w][qt * 16 + lo][1] = l_[qt];
        }
    }
    __syncthreads();

    // ---- combine 8 partials + epilogue ----
    const int q  = tid & 31;
    const int c0 = (tid >> 5) * 4;

    float gm = -3.0e38f;
    #pragma unroll
    for (int s2 = 0; s2 < NW; ++s2) gm = fmaxf(gm, mlbuf[s2][q][0]);

    float Ls = 0.f, O[4] = { 0.f, 0.f, 0.f, 0.f };
    #pragma unroll
    for (int s2 = 0; s2 < NW; ++s2) {
        const float cf = __expf(mlbuf[s2][q][0] - gm);
        Ls += mlbuf[s2][q][1] * cf;
        #pragma unroll
        for (int k = 0; k < 4; ++k)
            O[k] += smem[s2][q * 65 + c0 + k] * cf;
    }
    const float rl    = __builtin_amdgcn_rcpf(Ls);
    const float alpha = alphap[0];

    #pragma unroll
    for (int k = 0; k < 4; ++k) {
        const size_t idx = ((size_t)(nb * NCH + c0 + k)) * L_SEQ + i0 + q;
        out[idx] = alpha * O[k] * rl + x[idx];
    }
}

extern "C" void kernel_launch(void* const* d_in, const int* in_sizes, int n_in,
                              void* d_out, int out_size, void* d_ws, size_t ws_size,
                              hipStream_t stream) {
    const float* x     = (const float*)d_in[0];
    const float* wb    = (const float*)d_in[1];
    const float* bb    = (const float*)d_in[2];
    const float* wc    = (const float*)d_in[3];
    const float* bc    = (const float*)d_in[4];
    const float* wd    = (const float*)d_in[5];
    const float* bd    = (const float*)d_in[6];
    const float* alpha = (const float*)d_in[7];

    const size_t elems = (size_t)NBATCH * L_SEQ * NCH;  // 1,048,576 bytes each (fp8)
    u8* Qp8 = (u8*)d_ws;
    u8* Kp8 = Qp8 + elems;
    u8* Vp8 = Kp8 + elems;

    qkv_kernel<<<dim3(L_SEQ / 64, NBATCH), 256, 0, stream>>>(
        x, wb, bb, wc, bc, wd, bd, Qp8, Kp8, Vp8);
    attn_kernel<<<dim3(L_SEQ / QB, NBATCH), 512, 0, stream>>>(
        Qp8, Kp8, Vp8, x, alpha, (float*)d_out);
}